// Round 2
// baseline (1631.619 us; speedup 1.0000x reference)
//
#include <hip/hip_runtime.h>
#include <hip/hip_bf16.h>
#include <type_traits>

typedef __hip_bfloat16 bf16;
typedef __attribute__((ext_vector_type(8))) short short8;
typedef __attribute__((ext_vector_type(4))) float floatx4;

static constexpr int kNumItem = 50000;

__device__ __forceinline__ float bf2f(const bf16 x) { return __bfloat162float(x); }

union alignas(16) Pack8 {
  bf16 b[8];
  short8 s;
};

__device__ __forceinline__ void async_cp16(const void* g, void* l) {
  __builtin_amdgcn_global_load_lds((const __attribute__((address_space(1))) void*)g,
                                   (__attribute__((address_space(3))) void*)l, 16, 0, 0);
}

// ---------------- per-row 1/max(||x||,1e-12), fp32 input ----------------
__global__ __launch_bounds__(256) void row_invnorm(const float* __restrict__ X,
                                                   float* __restrict__ out,
                                                   int M, int K) {
  const int lane = threadIdx.x & 63;
  const int wave = threadIdx.x >> 6;
  const int row = blockIdx.x * 4 + wave;
  if (row >= M) return;
  const float* xr = X + (size_t)row * K;
  float s = 0.f;
  for (int c = lane * 8; c < K; c += 64 * 8) {
    float4 a = *(const float4*)(xr + c);
    float4 b = *(const float4*)(xr + c + 4);
    s += a.x * a.x + a.y * a.y + a.z * a.z + a.w * a.w;
    s += b.x * b.x + b.y * b.y + b.z * b.z + b.w * b.w;
  }
#pragma unroll
  for (int off = 32; off > 0; off >>= 1) s += __shfl_xor(s, off, 64);
  if (lane == 0) out[row] = 1.0f / fmaxf(sqrtf(s), 1e-12f);
}

// ---------------- NT GEMM: C[M,N] = act(scale_m * (A[M,K] @ B[N,K]^T) + bias[N]) ----
// m97-style 128-tile; bf16 MFMA. fp32 sources are converted to bf16 during
// LDS staging (float4 loads + pack + 16B ds_write); bf16 sources use
// global_load_lds width=16. C/D layout col=lane&15, row=quad*4+r (m89/m91).
template <int BM, int BN, typename AT, typename BT, typename CT>
__global__ __launch_bounds__(256) void gemm_bt(const AT* __restrict__ A,
                                               const BT* __restrict__ B,
                                               CT* __restrict__ C,
                                               int M, int N, int K,
                                               const float* __restrict__ rowScale,
                                               const float* __restrict__ bias,
                                               int doRelu) {
  constexpr int BK = 32;
  __shared__ __align__(16) bf16 sA[BM * BK];
  __shared__ __align__(16) bf16 sB[BN * BK];
  const int t = threadIdx.x;
  const int lane = t & 63;
  const int wave = t >> 6;
  constexpr int WN = BN / 64;  // waves along N
  const int wm = wave / WN;
  const int wn = wave % WN;
  const int m0 = blockIdx.y * BM;
  const int n0 = blockIdx.x * BN;
  const int lane16 = lane & 15;
  const int quad = lane >> 4;

  floatx4 acc[4][4];
#pragma unroll
  for (int i = 0; i < 4; i++)
#pragma unroll
    for (int j = 0; j < 4; j++) acc[i][j] = (floatx4)0.0f;

  for (int k0 = 0; k0 < K; k0 += BK) {
    // stage A tile: BM rows x 32 bf16 (4 chunks of 8 elems per row)
#pragma unroll
    for (int it = 0; it < BM / 64; ++it) {
      int c = t + 256 * it;
      int row = c >> 2;
      int col = (c & 3) * 8;
      int gr = m0 + row;
      if (gr > M - 1) gr = M - 1;  // clamp: safe re-read, stores are guarded
      if constexpr (std::is_same_v<AT, bf16>) {
        async_cp16(A + (size_t)gr * K + k0 + col, &sA[c * 8]);
      } else {
        const float* src = A + (size_t)gr * K + k0 + col;
        float4 fa = *(const float4*)src;
        float4 fb = *(const float4*)(src + 4);
        Pack8 p;
        p.b[0] = __float2bfloat16(fa.x); p.b[1] = __float2bfloat16(fa.y);
        p.b[2] = __float2bfloat16(fa.z); p.b[3] = __float2bfloat16(fa.w);
        p.b[4] = __float2bfloat16(fb.x); p.b[5] = __float2bfloat16(fb.y);
        p.b[6] = __float2bfloat16(fb.z); p.b[7] = __float2bfloat16(fb.w);
        *(short8*)(void*)&sA[c * 8] = p.s;
      }
    }
    // stage B tile (weights, N rows x K)
#pragma unroll
    for (int it = 0; it < BN / 64; ++it) {
      int c = t + 256 * it;
      int row = c >> 2;
      int col = (c & 3) * 8;
      int gr = n0 + row;
      if (gr > N - 1) gr = N - 1;
      if constexpr (std::is_same_v<BT, bf16>) {
        async_cp16(B + (size_t)gr * K + k0 + col, &sB[c * 8]);
      } else {
        const float* src = B + (size_t)gr * K + k0 + col;
        float4 fa = *(const float4*)src;
        float4 fb = *(const float4*)(src + 4);
        Pack8 p;
        p.b[0] = __float2bfloat16(fa.x); p.b[1] = __float2bfloat16(fa.y);
        p.b[2] = __float2bfloat16(fa.z); p.b[3] = __float2bfloat16(fa.w);
        p.b[4] = __float2bfloat16(fb.x); p.b[5] = __float2bfloat16(fb.y);
        p.b[6] = __float2bfloat16(fb.z); p.b[7] = __float2bfloat16(fb.w);
        *(short8*)(void*)&sB[c * 8] = p.s;
      }
    }
    __syncthreads();

    short8 afr[4], bfr[4];
#pragma unroll
    for (int i = 0; i < 4; i++)
      afr[i] = *(const short8*)(const void*)&sA[(wm * 64 + i * 16 + lane16) * BK + quad * 8];
#pragma unroll
    for (int j = 0; j < 4; j++)
      bfr[j] = *(const short8*)(const void*)&sB[(wn * 64 + j * 16 + lane16) * BK + quad * 8];
#pragma unroll
    for (int i = 0; i < 4; i++)
#pragma unroll
      for (int j = 0; j < 4; j++)
        acc[i][j] = __builtin_amdgcn_mfma_f32_16x16x32_bf16(afr[i], bfr[j], acc[i][j], 0, 0, 0);
    __syncthreads();
  }

  // epilogue
#pragma unroll
  for (int i = 0; i < 4; i++) {
#pragma unroll
    for (int j = 0; j < 4; j++) {
      const int col = n0 + wn * 64 + j * 16 + lane16;
      const float bv = bias[col];
#pragma unroll
      for (int r = 0; r < 4; r++) {
        const int row = m0 + wm * 64 + i * 16 + quad * 4 + r;
        if (row < M) {
          float v = acc[i][j][r];
          if (rowScale) v *= rowScale[row];
          v += bv;
          if (doRelu) v = v > 0.f ? v : 0.f;
          if constexpr (std::is_same_v<CT, bf16>)
            C[(size_t)row * N + col] = __float2bfloat16(v);
          else
            C[(size_t)row * N + col] = v;
        }
      }
    }
  }
}

// ---------------- per-token fusion: gather -> l2norm -> LN -> qkv -> attn -> mean ----
__global__ __launch_bounds__(256) void fuse_attn(const int* __restrict__ seq,
                                                 const bf16* __restrict__ c_emb,
                                                 const bf16* __restrict__ t_emb,
                                                 const bf16* __restrict__ cf_emb,
                                                 const float* __restrict__ id_emb,
                                                 const float* __restrict__ wq,
                                                 const float* __restrict__ wk,
                                                 const float* __restrict__ wv,
                                                 float* __restrict__ out, int n_tok) {
  // weights in fp32 LDS, row stride 68 floats (16B-aligned rows, spreads banks)
  __shared__ __align__(16) float sw[3][64 * 68];
  __shared__ __align__(16) float sxn[4][4][64];
  const int t = threadIdx.x;
  const int lane = t & 63;
  const int wave = t >> 6;

  for (int idx = t; idx < 4096; idx += 256) {
    int r = idx >> 6, c = idx & 63;
    sw[0][r * 68 + c] = wq[idx];
    sw[1][r * 68 + c] = wk[idx];
    sw[2][r * 68 + c] = wv[idx];
  }
  __syncthreads();

  int token = blockIdx.x * 4 + wave;
  const int token_clamped = token < n_tok ? token : (n_tok - 1);
  int idx = seq[token_clamped];
  if (idx == kNumItem) idx = 0;
  if (idx < 0) idx = 0;
  if (idx > kNumItem - 1) idx = kNumItem - 1;

  float x[4];
  x[0] = bf2f(c_emb[(size_t)idx * 64 + lane]);
  x[1] = bf2f(t_emb[(size_t)idx * 64 + lane]);
  x[2] = bf2f(cf_emb[(size_t)idx * 64 + lane]);
  x[3] = id_emb[(size_t)idx * 64 + lane];

#pragma unroll
  for (int m = 0; m < 4; m++) {
    // l2norm over 64
    float ss = x[m] * x[m];
#pragma unroll
    for (int off = 32; off > 0; off >>= 1) ss += __shfl_xor(ss, off, 64);
    x[m] *= 1.0f / fmaxf(sqrtf(ss), 1e-12f);
    // LayerNorm (no affine) over 64
    float mu = x[m];
#pragma unroll
    for (int off = 32; off > 0; off >>= 1) mu += __shfl_xor(mu, off, 64);
    mu *= (1.0f / 64.0f);
    float d = x[m] - mu;
    float var = d * d;
#pragma unroll
    for (int off = 32; off > 0; off >>= 1) var += __shfl_xor(var, off, 64);
    var *= (1.0f / 64.0f);
    float xn = d * rsqrtf(var + 1e-5f);
    x[m] = xn;
    sxn[wave][m][lane] = xn;
  }
  __syncthreads();

  // q[m] = sum_d xn[m][d] * wq[lane][d]  (lane j owns output column j)
  float q[4] = {0, 0, 0, 0}, k[4] = {0, 0, 0, 0}, v[4] = {0, 0, 0, 0};
  for (int d4 = 0; d4 < 64; d4 += 4) {
    const float4 wq4 = *(const float4*)&sw[0][lane * 68 + d4];
    const float4 wk4 = *(const float4*)&sw[1][lane * 68 + d4];
    const float4 wv4 = *(const float4*)&sw[2][lane * 68 + d4];
#pragma unroll
    for (int m = 0; m < 4; m++) {
      const float4 xn4 = *(const float4*)&sxn[wave][m][d4];
      q[m] += xn4.x * wq4.x + xn4.y * wq4.y + xn4.z * wq4.z + xn4.w * wq4.w;
      k[m] += xn4.x * wk4.x + xn4.y * wk4.y + xn4.z * wk4.z + xn4.w * wk4.w;
      v[m] += xn4.x * wv4.x + xn4.y * wv4.y + xn4.z * wv4.z + xn4.w * wv4.w;
    }
  }

  // scores s[m][n] = (1/8) sum_j q[m][j] k[n][j] : butterfly-reduce 16 values
  float p[16];
#pragma unroll
  for (int m = 0; m < 4; m++)
#pragma unroll
    for (int n = 0; n < 4; n++) p[m * 4 + n] = q[m] * k[n];
#pragma unroll
  for (int off = 1; off < 64; off <<= 1)
#pragma unroll
    for (int i = 0; i < 16; i++) p[i] += __shfl_xor(p[i], off, 64);

  float abar[4] = {0, 0, 0, 0};
#pragma unroll
  for (int m = 0; m < 4; m++) {
    float s0 = p[m * 4 + 0] * 0.125f, s1 = p[m * 4 + 1] * 0.125f;
    float s2 = p[m * 4 + 2] * 0.125f, s3 = p[m * 4 + 3] * 0.125f;
    float mx = fmaxf(fmaxf(s0, s1), fmaxf(s2, s3));
    float e0 = expf(s0 - mx), e1 = expf(s1 - mx), e2 = expf(s2 - mx), e3 = expf(s3 - mx);
    float inv = 1.0f / (e0 + e1 + e2 + e3);
    abar[0] += e0 * inv;
    abar[1] += e1 * inv;
    abar[2] += e2 * inv;
    abar[3] += e3 * inv;
  }
  float o = 0.25f * (abar[0] * v[0] + abar[1] * v[1] + abar[2] * v[2] + abar[3] * v[3]);
  if (token < n_tok) out[(size_t)token * 64 + lane] = o;
}

extern "C" void kernel_launch(void* const* d_in, const int* in_sizes, int n_in,
                              void* d_out, int out_size, void* d_ws, size_t ws_size,
                              hipStream_t stream) {
  const int* seq = (const int*)d_in[0];
  const float* content = (const float*)d_in[1];
  const float* text = (const float*)d_in[2];
  const float* cf_feat = (const float*)d_in[3];
  const float* item_emb = (const float*)d_in[4];
  const float* c_w1 = (const float*)d_in[5];
  const float* c_b1 = (const float*)d_in[6];
  const float* c_w2 = (const float*)d_in[7];
  const float* c_b2 = (const float*)d_in[8];
  const float* c_w3 = (const float*)d_in[9];
  const float* c_b3 = (const float*)d_in[10];
  const float* t_w1 = (const float*)d_in[11];
  const float* t_b1 = (const float*)d_in[12];
  const float* t_w2 = (const float*)d_in[13];
  const float* t_b2 = (const float*)d_in[14];
  const float* t_w3 = (const float*)d_in[15];
  const float* t_b3 = (const float*)d_in[16];
  const float* cf_w = (const float*)d_in[17];
  const float* cf_b = (const float*)d_in[18];
  const float* wq = (const float*)d_in[19];
  const float* wk = (const float*)d_in[20];
  const float* wv = (const float*)d_in[21];
  float* out = (float*)d_out;

  const int M = kNumItem;         // 50000
  const int n_tok = in_sizes[0];  // 51200

  // workspace carve-up (~149 MB)
  char* w = (char*)d_ws;
  size_t off = 0;
  auto alloc = [&](size_t bytes) -> void* {
    void* p = w + off;
    off += (bytes + 255) & ~(size_t)255;
    return p;
  };
  float* invn_c = (float*)alloc((size_t)M * 4);
  float* invn_t = (float*)alloc((size_t)M * 4);
  bf16* c_emb = (bf16*)alloc((size_t)M * 64 * 2);
  bf16* t_emb = (bf16*)alloc((size_t)M * 64 * 2);
  bf16* cf_emb = (bf16*)alloc((size_t)M * 64 * 2);
  bf16* H1 = (bf16*)alloc((size_t)M * 1024 * 2);  // reused by text chain (768 cols)
  bf16* H2 = (bf16*)alloc((size_t)M * 256 * 2);

  // 1. row inverse norms (content: K=1024, text: K=768)
  row_invnorm<<<dim3((M + 3) / 4), dim3(256), 0, stream>>>(content, invn_c, M, 1024);
  row_invnorm<<<dim3((M + 3) / 4), dim3(256), 0, stream>>>(text, invn_t, M, 768);

  // 2. content chain
  gemm_bt<128, 128, float, float, bf16>
      <<<dim3(1024 / 128, (M + 127) / 128), dim3(256), 0, stream>>>(
          content, c_w1, H1, M, 1024, 1024, invn_c, c_b1, 1);
  gemm_bt<128, 128, bf16, float, bf16>
      <<<dim3(256 / 128, (M + 127) / 128), dim3(256), 0, stream>>>(
          H1, c_w2, H2, M, 256, 1024, nullptr, c_b2, 1);
  gemm_bt<256, 64, bf16, float, bf16>
      <<<dim3(1, (M + 255) / 256), dim3(256), 0, stream>>>(
          H2, c_w3, c_emb, M, 64, 256, nullptr, c_b3, 0);

  // 3. text chain (H1/H2 reused; stream-ordered)
  gemm_bt<128, 128, float, float, bf16>
      <<<dim3(768 / 128, (M + 127) / 128), dim3(256), 0, stream>>>(
          text, t_w1, H1, M, 768, 768, invn_t, t_b1, 1);
  gemm_bt<128, 128, bf16, float, bf16>
      <<<dim3(256 / 128, (M + 127) / 128), dim3(256), 0, stream>>>(
          H1, t_w2, H2, M, 256, 768, nullptr, t_b2, 1);
  gemm_bt<256, 64, bf16, float, bf16>
      <<<dim3(1, (M + 255) / 256), dim3(256), 0, stream>>>(
          H2, t_w3, t_emb, M, 64, 256, nullptr, t_b3, 0);

  // 4. cf projection
  gemm_bt<256, 64, float, float, bf16>
      <<<dim3(1, (M + 255) / 256), dim3(256), 0, stream>>>(
          cf_feat, cf_w, cf_emb, M, 64, 64, nullptr, cf_b, 0);

  // 5. per-token fusion
  fuse_attn<<<dim3((n_tok + 3) / 4), dim3(256), 0, stream>>>(
      seq, c_emb, t_emb, cf_emb, item_emb, wq, wk, wv, out, n_tok);
}

// Round 3
// 1418.347 us; speedup vs baseline: 1.1504x; 1.1504x over previous
//
#include <hip/hip_runtime.h>
#include <hip/hip_bf16.h>
#include <type_traits>

typedef __hip_bfloat16 bf16;
typedef __attribute__((ext_vector_type(8))) short short8;
typedef __attribute__((ext_vector_type(4))) float floatx4;

static constexpr int kNumItem = 50000;

__device__ __forceinline__ float bf2f(const bf16 x) { return __bfloat162float(x); }

union alignas(16) Pack8 {
  bf16 b[8];
  short8 s;
};
union alignas(8) Pack4 {
  bf16 b[4];
  short4 s;
};

__device__ __forceinline__ void async_cp16(const void* g, void* l) {
  __builtin_amdgcn_global_load_lds((const __attribute__((address_space(1))) void*)g,
                                   (__attribute__((address_space(3))) void*)l, 16, 0, 0);
}

// ---------------- per-row 1/max(||x||,1e-12), fp32 input (slim path) ------------
__global__ __launch_bounds__(256) void row_invnorm(const float* __restrict__ X,
                                                   float* __restrict__ out,
                                                   int M, int K) {
  const int lane = threadIdx.x & 63;
  const int wave = threadIdx.x >> 6;
  const int row = blockIdx.x * 4 + wave;
  if (row >= M) return;
  const float* xr = X + (size_t)row * K;
  float s = 0.f;
  for (int c = lane * 8; c < K; c += 64 * 8) {
    float4 a = *(const float4*)(xr + c);
    float4 b = *(const float4*)(xr + c + 4);
    s += a.x * a.x + a.y * a.y + a.z * a.z + a.w * a.w;
    s += b.x * b.x + b.y * b.y + b.z * b.z + b.w * b.w;
  }
#pragma unroll
  for (int off = 32; off > 0; off >>= 1) s += __shfl_xor(s, off, 64);
  if (lane == 0) out[row] = 1.0f / fmaxf(sqrtf(s), 1e-12f);
}

// ------------- fused: fp32 row -> bf16 row copy + 1/||row|| (fat path) ----------
__global__ __launch_bounds__(256) void cvt_rows_norm(const float* __restrict__ X,
                                                     bf16* __restrict__ Xb,
                                                     float* __restrict__ out,
                                                     int M, int K) {
  const int lane = threadIdx.x & 63;
  const int wave = threadIdx.x >> 6;
  const int row = blockIdx.x * 4 + wave;
  if (row >= M) return;
  const float* xr = X + (size_t)row * K;
  bf16* dr = Xb + (size_t)row * K;
  float s = 0.f;
  for (int c = lane * 8; c < K; c += 64 * 8) {
    float4 a = *(const float4*)(xr + c);
    float4 b = *(const float4*)(xr + c + 4);
    s += a.x * a.x + a.y * a.y + a.z * a.z + a.w * a.w;
    s += b.x * b.x + b.y * b.y + b.z * b.z + b.w * b.w;
    Pack8 p;
    p.b[0] = __float2bfloat16(a.x); p.b[1] = __float2bfloat16(a.y);
    p.b[2] = __float2bfloat16(a.z); p.b[3] = __float2bfloat16(a.w);
    p.b[4] = __float2bfloat16(b.x); p.b[5] = __float2bfloat16(b.y);
    p.b[6] = __float2bfloat16(b.z); p.b[7] = __float2bfloat16(b.w);
    *(short8*)(void*)(dr + c) = p.s;
  }
#pragma unroll
  for (int off = 32; off > 0; off >>= 1) s += __shfl_xor(s, off, 64);
  if (lane == 0) out[row] = 1.0f / fmaxf(sqrtf(s), 1e-12f);
}

// ---------------- pack 7 fp32 weight matrices -> one contiguous bf16 region -----
struct WPack {
  const float* src[7];
  int start4[7];  // chunk (float4) start offset of each segment in the concat
  int total4;
};
__global__ __launch_bounds__(256) void cvt_many(WPack p, bf16* __restrict__ dst) {
  int c = blockIdx.x * 256 + threadIdx.x;
  const int stride = gridDim.x * 256;
  for (; c < p.total4; c += stride) {
    int s = 0;
#pragma unroll
    for (int k = 1; k < 7; k++)
      if (c >= p.start4[k]) s = k;
    const float4 v = ((const float4*)p.src[s])[c - p.start4[s]];
    Pack4 q;
    q.b[0] = __float2bfloat16(v.x); q.b[1] = __float2bfloat16(v.y);
    q.b[2] = __float2bfloat16(v.z); q.b[3] = __float2bfloat16(v.w);
    *(short4*)(void*)(dst + (size_t)c * 4) = q.s;
  }
}

// ---------------- NT GEMM: C[M,N] = act(scale_m * (A[M,K] @ B[N,K]^T) + bias[N]) ----
// m97-style 128-tile; bf16 MFMA; bf16 sources staged via global_load_lds(16B);
// fp32 sources converted during LDS staging. C/D layout col=lane&15, row=quad*4+r.
template <int BM, int BN, typename AT, typename BT, typename CT>
__global__ __launch_bounds__(256) void gemm_bt(const AT* __restrict__ A,
                                               const BT* __restrict__ B,
                                               CT* __restrict__ C,
                                               int M, int N, int K,
                                               const float* __restrict__ rowScale,
                                               const float* __restrict__ bias,
                                               int doRelu) {
  constexpr int BK = 32;
  __shared__ __align__(16) bf16 sA[BM * BK];
  __shared__ __align__(16) bf16 sB[BN * BK];
  const int t = threadIdx.x;
  const int lane = t & 63;
  const int wave = t >> 6;
  constexpr int WN = BN / 64;  // waves along N
  const int wm = wave / WN;
  const int wn = wave % WN;
  const int m0 = blockIdx.y * BM;
  const int n0 = blockIdx.x * BN;
  const int lane16 = lane & 15;
  const int quad = lane >> 4;

  floatx4 acc[4][4];
#pragma unroll
  for (int i = 0; i < 4; i++)
#pragma unroll
    for (int j = 0; j < 4; j++) acc[i][j] = (floatx4)0.0f;

  for (int k0 = 0; k0 < K; k0 += BK) {
    // stage A tile: BM rows x 32 bf16 (4 chunks of 8 elems per row)
#pragma unroll
    for (int it = 0; it < BM / 64; ++it) {
      int c = t + 256 * it;
      int row = c >> 2;
      int col = (c & 3) * 8;
      int gr = m0 + row;
      if (gr > M - 1) gr = M - 1;  // clamp: safe re-read, stores are guarded
      if constexpr (std::is_same_v<AT, bf16>) {
        async_cp16(A + (size_t)gr * K + k0 + col, &sA[c * 8]);
      } else {
        const float* src = A + (size_t)gr * K + k0 + col;
        float4 fa = *(const float4*)src;
        float4 fb = *(const float4*)(src + 4);
        Pack8 p;
        p.b[0] = __float2bfloat16(fa.x); p.b[1] = __float2bfloat16(fa.y);
        p.b[2] = __float2bfloat16(fa.z); p.b[3] = __float2bfloat16(fa.w);
        p.b[4] = __float2bfloat16(fb.x); p.b[5] = __float2bfloat16(fb.y);
        p.b[6] = __float2bfloat16(fb.z); p.b[7] = __float2bfloat16(fb.w);
        *(short8*)(void*)&sA[c * 8] = p.s;
      }
    }
    // stage B tile (weights, N rows x K)
#pragma unroll
    for (int it = 0; it < BN / 64; ++it) {
      int c = t + 256 * it;
      int row = c >> 2;
      int col = (c & 3) * 8;
      int gr = n0 + row;
      if (gr > N - 1) gr = N - 1;
      if constexpr (std::is_same_v<BT, bf16>) {
        async_cp16(B + (size_t)gr * K + k0 + col, &sB[c * 8]);
      } else {
        const float* src = B + (size_t)gr * K + k0 + col;
        float4 fa = *(const float4*)src;
        float4 fb = *(const float4*)(src + 4);
        Pack8 p;
        p.b[0] = __float2bfloat16(fa.x); p.b[1] = __float2bfloat16(fa.y);
        p.b[2] = __float2bfloat16(fa.z); p.b[3] = __float2bfloat16(fa.w);
        p.b[4] = __float2bfloat16(fb.x); p.b[5] = __float2bfloat16(fb.y);
        p.b[6] = __float2bfloat16(fb.z); p.b[7] = __float2bfloat16(fb.w);
        *(short8*)(void*)&sB[c * 8] = p.s;
      }
    }
    __syncthreads();

    short8 afr[4], bfr[4];
#pragma unroll
    for (int i = 0; i < 4; i++)
      afr[i] = *(const short8*)(const void*)&sA[(wm * 64 + i * 16 + lane16) * BK + quad * 8];
#pragma unroll
    for (int j = 0; j < 4; j++)
      bfr[j] = *(const short8*)(const void*)&sB[(wn * 64 + j * 16 + lane16) * BK + quad * 8];
#pragma unroll
    for (int i = 0; i < 4; i++)
#pragma unroll
      for (int j = 0; j < 4; j++)
        acc[i][j] = __builtin_amdgcn_mfma_f32_16x16x32_bf16(afr[i], bfr[j], acc[i][j], 0, 0, 0);
    __syncthreads();
  }

  // epilogue
#pragma unroll
  for (int i = 0; i < 4; i++) {
#pragma unroll
    for (int j = 0; j < 4; j++) {
      const int col = n0 + wn * 64 + j * 16 + lane16;
      const float bv = bias[col];
#pragma unroll
      for (int r = 0; r < 4; r++) {
        const int row = m0 + wm * 64 + i * 16 + quad * 4 + r;
        if (row < M) {
          float v = acc[i][j][r];
          if (rowScale) v *= rowScale[row];
          v += bv;
          if (doRelu) v = v > 0.f ? v : 0.f;
          if constexpr (std::is_same_v<CT, bf16>)
            C[(size_t)row * N + col] = __float2bfloat16(v);
          else
            C[(size_t)row * N + col] = v;
        }
      }
    }
  }
}

// ---- per-token fusion v2: grid-stride tokens, weights loaded once per block ----
// LDS 52 KB (3 blocks/CU). swc chunk-major: [mat][d4][lane] float4 -> contiguous
// lane addresses, conflict-free. sxn is wave-private (no barrier in token loop).
__global__ __launch_bounds__(256) void fuse_attn2(const int* __restrict__ seq,
                                                  const bf16* __restrict__ c_emb,
                                                  const bf16* __restrict__ t_emb,
                                                  const bf16* __restrict__ cf_emb,
                                                  const float* __restrict__ id_emb,
                                                  const float* __restrict__ wq,
                                                  const float* __restrict__ wk,
                                                  const float* __restrict__ wv,
                                                  float* __restrict__ out, int n_tok) {
  __shared__ __align__(16) float4 swc[3072];  // 48 KB: [mat][d4][j]
  __shared__ float sxn[4][4][64];             // 4 KB: [wave][m][d]
  const int t = threadIdx.x;
  const int lane = t & 63;
  const int wave = t >> 6;

  for (int c = t; c < 3072; c += 256) {
    const int mat = c >> 10, rem = c & 1023, d4 = rem >> 6, j = rem & 63;
    const float* W = (mat == 0) ? wq : (mat == 1 ? wk : wv);
    swc[c] = *(const float4*)(W + j * 64 + d4 * 4);
  }
  __syncthreads();

  const int gw = blockIdx.x * 4 + wave;
  const int gstride = gridDim.x * 4;
  for (int token = gw; token < n_tok; token += gstride) {
    int idx = seq[token];
    if (idx >= kNumItem || idx < 0) idx = 0;  // ref: padding index NUM_ITEM -> 0

    float x[4];
    x[0] = bf2f(c_emb[(size_t)idx * 64 + lane]);
    x[1] = bf2f(t_emb[(size_t)idx * 64 + lane]);
    x[2] = bf2f(cf_emb[(size_t)idx * 64 + lane]);
    x[3] = id_emb[(size_t)idx * 64 + lane];

#pragma unroll
    for (int m = 0; m < 4; m++) {
      // single 2-value butterfly: sum and sum-of-squares
      float sm = x[m], ss = x[m] * x[m];
#pragma unroll
      for (int off = 32; off > 0; off >>= 1) {
        sm += __shfl_xor(sm, off, 64);
        ss += __shfl_xor(ss, off, 64);
      }
      const float inv = 1.0f / fmaxf(sqrtf(ss), 1e-12f);
      const float xh = x[m] * inv;
      const float mu = sm * inv * (1.0f / 64.0f);
      const float ex2 = ss * inv * inv * (1.0f / 64.0f);
      const float var = ex2 - mu * mu;  // E[x^2] - mu^2
      const float xn = (xh - mu) * rsqrtf(var + 1e-5f);
      x[m] = xn;
      sxn[wave][m][lane] = xn;
    }
    // wave-private LDS round-trip: program order within the wave suffices.

    float q[4] = {0, 0, 0, 0}, kk[4] = {0, 0, 0, 0}, v[4] = {0, 0, 0, 0};
#pragma unroll
    for (int d4 = 0; d4 < 16; d4++) {
      const float4 a = swc[d4 * 64 + lane];
      const float4 b = swc[1024 + d4 * 64 + lane];
      const float4 g = swc[2048 + d4 * 64 + lane];
#pragma unroll
      for (int m = 0; m < 4; m++) {
        const float4 xn4 = *(const float4*)&sxn[wave][m][d4 * 4];
        q[m] += xn4.x * a.x + xn4.y * a.y + xn4.z * a.z + xn4.w * a.w;
        kk[m] += xn4.x * b.x + xn4.y * b.y + xn4.z * b.z + xn4.w * b.w;
        v[m] += xn4.x * g.x + xn4.y * g.y + xn4.z * g.z + xn4.w * g.w;
      }
    }

    // scores s[m][n] = (1/8) sum_j q[m][j] k[n][j]: butterfly-reduce 16 values
    float p[16];
#pragma unroll
    for (int m = 0; m < 4; m++)
#pragma unroll
      for (int n = 0; n < 4; n++) p[m * 4 + n] = q[m] * kk[n];
#pragma unroll
    for (int off = 1; off < 64; off <<= 1)
#pragma unroll
      for (int i = 0; i < 16; i++) p[i] += __shfl_xor(p[i], off, 64);

    float abar[4] = {0, 0, 0, 0};
#pragma unroll
    for (int m = 0; m < 4; m++) {
      float s0 = p[m * 4 + 0] * 0.125f, s1 = p[m * 4 + 1] * 0.125f;
      float s2 = p[m * 4 + 2] * 0.125f, s3 = p[m * 4 + 3] * 0.125f;
      float mx = fmaxf(fmaxf(s0, s1), fmaxf(s2, s3));
      float e0 = expf(s0 - mx), e1 = expf(s1 - mx), e2 = expf(s2 - mx), e3 = expf(s3 - mx);
      float inv = 1.0f / (e0 + e1 + e2 + e3);
      abar[0] += e0 * inv;
      abar[1] += e1 * inv;
      abar[2] += e2 * inv;
      abar[3] += e3 * inv;
    }
    const float o =
        0.25f * (abar[0] * v[0] + abar[1] * v[1] + abar[2] * v[2] + abar[3] * v[3]);
    out[(size_t)token * 64 + lane] = o;
  }
}

extern "C" void kernel_launch(void* const* d_in, const int* in_sizes, int n_in,
                              void* d_out, int out_size, void* d_ws, size_t ws_size,
                              hipStream_t stream) {
  const int* seq = (const int*)d_in[0];
  const float* content = (const float*)d_in[1];
  const float* text = (const float*)d_in[2];
  const float* cf_feat = (const float*)d_in[3];
  const float* item_emb = (const float*)d_in[4];
  const float* c_w1 = (const float*)d_in[5];
  const float* c_b1 = (const float*)d_in[6];
  const float* c_w2 = (const float*)d_in[7];
  const float* c_b2 = (const float*)d_in[8];
  const float* c_w3 = (const float*)d_in[9];
  const float* c_b3 = (const float*)d_in[10];
  const float* t_w1 = (const float*)d_in[11];
  const float* t_b1 = (const float*)d_in[12];
  const float* t_w2 = (const float*)d_in[13];
  const float* t_b2 = (const float*)d_in[14];
  const float* t_w3 = (const float*)d_in[15];
  const float* t_b3 = (const float*)d_in[16];
  const float* cf_w = (const float*)d_in[17];
  const float* cf_b = (const float*)d_in[18];
  const float* wq = (const float*)d_in[19];
  const float* wk = (const float*)d_in[20];
  const float* wv = (const float*)d_in[21];
  float* out = (float*)d_out;

  const int M = kNumItem;         // 50000
  const int n_tok = in_sizes[0];  // 51200

  // ---- workspace carve-up (ws_size-tiered) ----
  char* w = (char*)d_ws;
  size_t off = 0;
  auto alloc = [&](size_t bytes) -> void* {
    void* p = w + off;
    off += (bytes + 255) & ~(size_t)255;
    return p;
  };
  float* invn_c = (float*)alloc((size_t)M * 4);
  float* invn_t = (float*)alloc((size_t)M * 4);
  bf16* c_emb = (bf16*)alloc((size_t)M * 64 * 2);
  bf16* t_emb = (bf16*)alloc((size_t)M * 64 * 2);
  bf16* cf_emb = (bf16*)alloc((size_t)M * 64 * 2);
  bf16* H1 = (bf16*)alloc((size_t)M * 1024 * 2);  // reused by text chain
  bf16* H2 = (bf16*)alloc((size_t)M * 256 * 2);

  // bf16 weight pack: c_w1,c_w2,c_w3,t_w1,t_w2,t_w3,cf_w concatenated
  const int nw[7] = {1024 * 1024, 256 * 1024, 64 * 256, 768 * 768, 256 * 768, 64 * 256, 64 * 64};
  int wofs[8];
  wofs[0] = 0;
  for (int i = 0; i < 7; i++) wofs[i + 1] = wofs[i] + nw[i];
  bf16* Wb = (bf16*)alloc((size_t)wofs[7] * 2);
  const bool useWb = (off <= ws_size);
  bf16* Ab = (bf16*)alloc((size_t)M * 1024 * 2);  // bf16 copy of content/text (reused)
  const bool useAb = useWb && (off <= ws_size);

  if (useWb) {
    WPack p;
    for (int i = 0; i < 7; i++) {
      const float* srcs[7] = {c_w1, c_w2, c_w3, t_w1, t_w2, t_w3, cf_w};
      p.src[i] = srcs[i];
      p.start4[i] = wofs[i] / 4;
    }
    p.total4 = wofs[7] / 4;
    cvt_many<<<dim3(2048), dim3(256), 0, stream>>>(p, Wb);
  }

  if (useAb) {
    // ---- fat path: bf16 A + bf16 B everywhere big ----
    cvt_rows_norm<<<dim3((M + 3) / 4), dim3(256), 0, stream>>>(content, Ab, invn_c, M, 1024);
    gemm_bt<128, 128, bf16, bf16, bf16>
        <<<dim3(1024 / 128, (M + 127) / 128), dim3(256), 0, stream>>>(
            Ab, Wb + wofs[0], H1, M, 1024, 1024, invn_c, c_b1, 1);
    gemm_bt<128, 128, bf16, bf16, bf16>
        <<<dim3(256 / 128, (M + 127) / 128), dim3(256), 0, stream>>>(
            H1, Wb + wofs[1], H2, M, 256, 1024, nullptr, c_b2, 1);
    gemm_bt<256, 64, bf16, bf16, bf16>
        <<<dim3(1, (M + 255) / 256), dim3(256), 0, stream>>>(
            H2, Wb + wofs[2], c_emb, M, 64, 256, nullptr, c_b3, 0);

    cvt_rows_norm<<<dim3((M + 3) / 4), dim3(256), 0, stream>>>(text, Ab, invn_t, M, 768);
    gemm_bt<128, 128, bf16, bf16, bf16>
        <<<dim3(768 / 128, (M + 127) / 128), dim3(256), 0, stream>>>(
            Ab, Wb + wofs[3], H1, M, 768, 768, invn_t, t_b1, 1);
    gemm_bt<128, 128, bf16, bf16, bf16>
        <<<dim3(256 / 128, (M + 127) / 128), dim3(256), 0, stream>>>(
            H1, Wb + wofs[4], H2, M, 256, 768, nullptr, t_b2, 1);
    gemm_bt<256, 64, bf16, bf16, bf16>
        <<<dim3(1, (M + 255) / 256), dim3(256), 0, stream>>>(
            H2, Wb + wofs[5], t_emb, M, 64, 256, nullptr, t_b3, 0);

    gemm_bt<256, 64, float, bf16, bf16>
        <<<dim3(1, (M + 255) / 256), dim3(256), 0, stream>>>(
            cf_feat, Wb + wofs[6], cf_emb, M, 64, 64, nullptr, cf_b, 0);
  } else if (useWb) {
    // ---- slim path: fp32 A (packed in-kernel) + bf16 B ----
    row_invnorm<<<dim3((M + 3) / 4), dim3(256), 0, stream>>>(content, invn_c, M, 1024);
    row_invnorm<<<dim3((M + 3) / 4), dim3(256), 0, stream>>>(text, invn_t, M, 768);
    gemm_bt<128, 128, float, bf16, bf16>
        <<<dim3(1024 / 128, (M + 127) / 128), dim3(256), 0, stream>>>(
            content, Wb + wofs[0], H1, M, 1024, 1024, invn_c, c_b1, 1);
    gemm_bt<128, 128, bf16, bf16, bf16>
        <<<dim3(256 / 128, (M + 127) / 128), dim3(256), 0, stream>>>(
            H1, Wb + wofs[1], H2, M, 256, 1024, nullptr, c_b2, 1);
    gemm_bt<256, 64, bf16, bf16, bf16>
        <<<dim3(1, (M + 255) / 256), dim3(256), 0, stream>>>(
            H2, Wb + wofs[2], c_emb, M, 64, 256, nullptr, c_b3, 0);
    gemm_bt<128, 128, float, bf16, bf16>
        <<<dim3(768 / 128, (M + 127) / 128), dim3(256), 0, stream>>>(
            text, Wb + wofs[3], H1, M, 768, 768, invn_t, t_b1, 1);
    gemm_bt<128, 128, bf16, bf16, bf16>
        <<<dim3(256 / 128, (M + 127) / 128), dim3(256), 0, stream>>>(
            H1, Wb + wofs[4], H2, M, 256, 768, nullptr, t_b2, 1);
    gemm_bt<256, 64, bf16, bf16, bf16>
        <<<dim3(1, (M + 255) / 256), dim3(256), 0, stream>>>(
            H2, Wb + wofs[5], t_emb, M, 64, 256, nullptr, t_b3, 0);
    gemm_bt<256, 64, float, bf16, bf16>
        <<<dim3(1, (M + 255) / 256), dim3(256), 0, stream>>>(
            cf_feat, Wb + wofs[6], cf_emb, M, 64, 64, nullptr, cf_b, 0);
  } else {
    // ---- minimal path (round-2 behavior): fp32 A and B ----
    row_invnorm<<<dim3((M + 3) / 4), dim3(256), 0, stream>>>(content, invn_c, M, 1024);
    row_invnorm<<<dim3((M + 3) / 4), dim3(256), 0, stream>>>(text, invn_t, M, 768);
    gemm_bt<128, 128, float, float, bf16>
        <<<dim3(1024 / 128, (M + 127) / 128), dim3(256), 0, stream>>>(
            content, c_w1, H1, M, 1024, 1024, invn_c, c_b1, 1);
    gemm_bt<128, 128, bf16, float, bf16>
        <<<dim3(256 / 128, (M + 127) / 128), dim3(256), 0, stream>>>(
            H1, c_w2, H2, M, 256, 1024, nullptr, c_b2, 1);
    gemm_bt<256, 64, bf16, float, bf16>
        <<<dim3(1, (M + 255) / 256), dim3(256), 0, stream>>>(
            H2, c_w3, c_emb, M, 64, 256, nullptr, c_b3, 0);
    gemm_bt<128, 128, float, float, bf16>
        <<<dim3(768 / 128, (M + 127) / 128), dim3(256), 0, stream>>>(
            text, t_w1, H1, M, 768, 768, invn_t, t_b1, 1);
    gemm_bt<128, 128, bf16, float, bf16>
        <<<dim3(256 / 128, (M + 127) / 128), dim3(256), 0, stream>>>(
            H1, t_w2, H2, M, 256, 768, nullptr, t_b2, 1);
    gemm_bt<256, 64, bf16, float, bf16>
        <<<dim3(1, (M + 255) / 256), dim3(256), 0, stream>>>(
            H2, t_w3, t_emb, M, 64, 256, nullptr, t_b3, 0);
    gemm_bt<256, 64, float, float, bf16>
        <<<dim3(1, (M + 255) / 256), dim3(256), 0, stream>>>(
            cf_feat, cf_w, cf_emb, M, 64, 64, nullptr, cf_b, 0);
  }

  // ---- per-token fusion: 768 blocks = 3 resident/CU (52 KB LDS), grid-stride ----
  fuse_attn2<<<dim3(768), dim3(256), 0, stream>>>(
      seq, c_emb, t_emb, cf_emb, item_emb, wq, wk, wv, out, n_tok);
}